// Round 18
// baseline (100.396 us; speedup 1.0000x reference)
//
#include <hip/hip_runtime.h>
#include <hip/hip_fp16.h>

#define N_NODES 50000
#define K 32
#define NSEL 16
#define D 128
#define DOUT 64

typedef __attribute__((ext_vector_type(8))) _Float16 half8;
typedef __attribute__((ext_vector_type(4))) float floatx4;
typedef __attribute__((ext_vector_type(2))) float floatx2;

__device__ __forceinline__ unsigned int pack_h2(float a, float b) {
  union { __half2 h; unsigned int u; } c;
  c.h = __floats2half2_rn(a, b);
  return c.u;
}
__device__ __forceinline__ half8 as_h8(uint4 u) {
  union { uint4 u; half8 v; } c;
  c.u = u;
  return c.v;
}
__device__ __forceinline__ float fast_tanh(float x) {
  // 1 - 2/(1+e^{2x}). Exact at +/-inf.
  float e = __expf(2.f * x);
  return 1.f - __fdividef(2.f, 1.f + e);
}
__device__ __forceinline__ float agg_tanh(float s) {
  // tanh(s/16) = 1 - 2/(1+e^{s/8}); folds /16 and *2 into one constant.
  float e = __expf(s * 0.125f);
  return 1.f - __fdividef(2.f, 1.f + e);
}

// Kernel A: mlp2[n] = tanh(feat[n] @ W_mlp + b_mlp) (C=2), feat8 = fp8(feat).
// Blocks 0..15 additionally pre-pack W_lin into MFMA B-fragments (Whp).
// TWO nodes per wave. libm tanhf — mlp2 feeds top-k; fast tanh flips ties.
__global__ __launch_bounds__(256) void mlp_kernel(
    const float* __restrict__ feat, const float* __restrict__ Wm,
    const float* __restrict__ bm, const float* __restrict__ Wl,
    float2* __restrict__ mlp2,
    unsigned char* __restrict__ feat8 /* [N][D] fp8 e4m3, 128 B rows */,
    unsigned int* __restrict__ Whp /* 4096-word fp16 B-fragment table */) {
  const int wid = (blockIdx.x * blockDim.x + threadIdx.x) >> 6;  // 0..24999
  const int lane = threadIdx.x & 63;
  const int sub = lane & 31;
  const int n = wid * 2 + (lane >> 5);

  float4 f = *(const float4*)(feat + (size_t)n * D + sub * 4);
  float4 w01 = *(const float4*)(Wm + sub * 8);
  float4 w23 = *(const float4*)(Wm + sub * 8 + 4);
  float p0 = f.x * w01.x + f.y * w01.z + f.z * w23.x + f.w * w23.z;
  float p1 = f.x * w01.y + f.y * w01.w + f.z * w23.y + f.w * w23.w;
#pragma unroll
  for (int off = 16; off; off >>= 1) {  // stays within the 32-lane half
    p0 += __shfl_xor(p0, off);
    p1 += __shfl_xor(p1, off);
  }
  int pk8 = __builtin_amdgcn_cvt_pk_fp8_f32(f.x, f.y, 0, false);
  pk8 = __builtin_amdgcn_cvt_pk_fp8_f32(f.z, f.w, pk8, true);
  *(unsigned int*)(feat8 + ((size_t)n << 7) + (sub << 2)) = (unsigned int)pk8;
  if (sub == 0) {
    mlp2[n] = make_float2(tanhf(p0 + bm[0]), tanhf(p1 + bm[1]));
  }
  // W_lin fragment pre-pack: word wd = ((kk*4+nt)*64 + l)*4 + j2
  if (blockIdx.x < 16) {
    const int wd = blockIdx.x * 256 + threadIdx.x;  // 0..4095
    const int fr = wd >> 8, l = (wd >> 2) & 63, j2 = wd & 3;
    const int kk = fr >> 2, nt = fr & 3;
    const int k = kk * 32 + ((l >> 4) << 3) + 2 * j2;
    const int nn = nt * 16 + (l & 15);
    Whp[wd] = pack_h2(Wl[k * DOUT + nn], Wl[(k + 1) * DOUT + nn]);
  }
}

// Kernel B (fused): 512 threads = 8 waves = 16 nodes = one MFMA m-tile.
// Rank: fast f32 strict-less compares; exact when no ties. Tie detection is
// EXACT: sum of strict-less ranks over the half = C(32,2)*3 - #tied-pairs,
// so butterfly-sum != 1488 iff a tie exists; rare fallback (~3% of halves,
// duplicate neighbor ids) recomputes with u64 keys (bits(d)<<32)|j whose
// lexicographic < is EXACTLY top_k's tie-break. Output bit-identical.
// Gather: pre-shifted src (<<7) through rank permute; fp8 rows; f32 pk
// accumulation in t-order. h packed fp16 into LDS; waves 0..3 do the
// out = h @ W_lin + b matmul via 4 fp16 MFMAs each.
__global__ __launch_bounds__(512) void care_gemm_kernel(
    const float* __restrict__ feat, const unsigned char* __restrict__ feat8,
    const float2* __restrict__ mlp2, const int* __restrict__ nbr0,
    const int* __restrict__ nbr1, const int* __restrict__ nbr2,
    const unsigned int* __restrict__ Whp, const float* __restrict__ bl,
    float* __restrict__ out) {
  __shared__ __align__(16) unsigned int sW[4096];    // 16 KB B-fragments
  __shared__ __align__(16) unsigned int sH[16][68];  // 4.25 KB padded h rows

  const int tid = threadIdx.x;
  // Stage pre-packed W fragments: 4096 / 512 = 8 coalesced words each.
#pragma unroll
  for (int i = 0; i < 8; ++i) sW[tid + i * 512] = Whp[tid + i * 512];

  const int lane = tid & 63;
  const int sub = lane & 31;
  const int h = lane >> 5;
  const int w = tid >> 6;              // wave 0..7
  const int nl = w * 2 + h;            // node-local 0..15
  const int hbase = (lane & 32) << 2;  // DS byte addr of half's lane 0
  const int n = blockIdx.x * 16 + nl;  // grid = 3125 blocks exactly

  const float2 my = mlp2[n];
  float4 acc = *(const float4*)(feat + (size_t)n * D + sub * 4);  // residual

  // Phase 1: all edge ids + their mlp2 rows (6 loads in flight)
  const int src0 = nbr0[n * K + sub];
  const int src1 = nbr1[n * K + sub];
  const int src2 = nbr2[n * K + sub];
  const float2 mh0 = mlp2[src0];
  const float2 mh1 = mlp2[src1];
  const float2 mh2 = mlp2[src2];
  const float d0 = fabsf(mh0.x - my.x) + fabsf(mh0.y - my.y);
  const float d1 = fabsf(mh1.x - my.x) + fabsf(mh1.y - my.y);
  const float d2 = fabsf(mh2.x - my.x) + fabsf(mh2.y - my.y);
  const int b0 = __float_as_int(d0);
  const int b1 = __float_as_int(d1);
  const int b2 = __float_as_int(d2);

  // Phase 2a: fast strict-less f32 rank (2 VALU/compare)
  int c0 = 0, c1 = 0, c2 = 0;
#pragma unroll
  for (int j = 0; j < K; ++j) {
    const int aj = hbase + 4 * j;
    const float a0 = __int_as_float(__builtin_amdgcn_ds_bpermute(aj, b0));
    const float a1 = __int_as_float(__builtin_amdgcn_ds_bpermute(aj, b1));
    const float a2 = __int_as_float(__builtin_amdgcn_ds_bpermute(aj, b2));
    c0 += a0 < d0;
    c1 += a1 < d1;
    c2 += a2 < d2;
  }
  // Phase 2b: exact tie detection — butterfly-sum within the 32-lane half.
  int s = c0 + c1 + c2;
#pragma unroll
  for (int off = 1; off <= 16; off <<= 1) s += __shfl_xor(s, off);
  if (s != 3 * (K * (K - 1) / 2)) {  // 1488: a tie exists in this half
    const unsigned long long ki0 =
        ((unsigned long long)(unsigned)b0 << 32) | (unsigned)sub;
    const unsigned long long ki1 =
        ((unsigned long long)(unsigned)b1 << 32) | (unsigned)sub;
    const unsigned long long ki2 =
        ((unsigned long long)(unsigned)b2 << 32) | (unsigned)sub;
    c0 = 0; c1 = 0; c2 = 0;
#pragma unroll
    for (int j = 0; j < K; ++j) {
      const int aj = hbase + 4 * j;
      const unsigned a0 = (unsigned)__builtin_amdgcn_ds_bpermute(aj, b0);
      const unsigned a1 = (unsigned)__builtin_amdgcn_ds_bpermute(aj, b1);
      const unsigned a2 = (unsigned)__builtin_amdgcn_ds_bpermute(aj, b2);
      c0 += (((unsigned long long)a0 << 32) | (unsigned)j) < ki0;
      c1 += (((unsigned long long)a1 << 32) | (unsigned)j) < ki1;
      c2 += (((unsigned long long)a2 << 32) | (unsigned)j) < ki2;
    }
  }

  // push PRE-SHIFTED src (row byte-offset) to lane hbase/4 + rank
  int p0 = __builtin_amdgcn_ds_permute(hbase + (c0 << 2), src0 << 7);
  int p1 = __builtin_amdgcn_ds_permute(hbase + (c1 << 2), src1 << 7);
  int p2 = __builtin_amdgcn_ds_permute(hbase + (c2 << 2), src2 << 7);

  // Phase 3: merged gather — 32-bit indices off the uniform feat8 base,
  // packed f32 accumulation in t-order (bit-identical to R11).
  const unsigned off4 = (unsigned)sub << 2;
  floatx2 A00 = {0.f, 0.f}, A01 = {0.f, 0.f};
  floatx2 A10 = {0.f, 0.f}, A11 = {0.f, 0.f};
  floatx2 A20 = {0.f, 0.f}, A21 = {0.f, 0.f};
#pragma unroll
  for (int t = 0; t < NSEL; ++t) {
    const int at = hbase + 4 * t;
    const unsigned r0 = (unsigned)__builtin_amdgcn_ds_bpermute(at, p0);
    const unsigned r1 = (unsigned)__builtin_amdgcn_ds_bpermute(at, p1);
    const unsigned r2 = (unsigned)__builtin_amdgcn_ds_bpermute(at, p2);
    const unsigned w0 = *(const unsigned*)(feat8 + (r0 | off4));
    const unsigned w1 = *(const unsigned*)(feat8 + (r1 | off4));
    const unsigned w2 = *(const unsigned*)(feat8 + (r2 | off4));
    A00 += __builtin_amdgcn_cvt_pk_f32_fp8(w0, false);
    A01 += __builtin_amdgcn_cvt_pk_f32_fp8(w0, true);
    A10 += __builtin_amdgcn_cvt_pk_f32_fp8(w1, false);
    A11 += __builtin_amdgcn_cvt_pk_f32_fp8(w1, true);
    A20 += __builtin_amdgcn_cvt_pk_f32_fp8(w2, false);
    A21 += __builtin_amdgcn_cvt_pk_f32_fp8(w2, true);
  }
  acc.x += 0.5f * agg_tanh(A00.x);
  acc.y += 0.5f * agg_tanh(A00.y);
  acc.z += 0.5f * agg_tanh(A01.x);
  acc.w += 0.5f * agg_tanh(A01.y);
  acc.x += 0.5f * agg_tanh(A10.x);
  acc.y += 0.5f * agg_tanh(A10.y);
  acc.z += 0.5f * agg_tanh(A11.x);
  acc.w += 0.5f * agg_tanh(A11.y);
  acc.x += 0.5f * agg_tanh(A20.x);
  acc.y += 0.5f * agg_tanh(A20.y);
  acc.z += 0.5f * agg_tanh(A21.x);
  acc.w += 0.5f * agg_tanh(A21.y);

  acc.x = fast_tanh(acc.x);
  acc.y = fast_tanh(acc.y);
  acc.z = fast_tanh(acc.z);
  acc.w = fast_tanh(acc.w);
  uint2 hp;
  hp.x = pack_h2(acc.x, acc.y);
  hp.y = pack_h2(acc.z, acc.w);
  *(uint2*)&sH[nl][sub * 2] = hp;  // h row in LDS (fp16-packed)
  __syncthreads();                 // covers sW staging + sH writes

  // Matmul epilogue: waves 0..3, one 16-col n-block each; 4 MFMAs over K=128.
  if (w < 4) {
    const int nt = w;
    const int m = lane & 15;
    const int koff = (lane >> 4) * 4;  // word offset inside 16-word k-chunk
    float bn = bl[nt * 16 + m];
    floatx4 c4 = {bn, bn, bn, bn};
#pragma unroll
    for (int kk = 0; kk < 4; ++kk) {
      uint4 aw = *(const uint4*)&sH[m][kk * 16 + koff];
      uint4 bw = *(const uint4*)&sW[(kk * 4 + nt) * 256 + lane * 4];
      c4 = __builtin_amdgcn_mfma_f32_16x16x32_f16(as_h8(aw), as_h8(bw), c4, 0,
                                                  0, 0);
    }
#pragma unroll
    for (int r = 0; r < 4; ++r) {
      const int mr = ((lane >> 4) << 2) + r;
      out[(size_t)(blockIdx.x * 16 + mr) * DOUT + nt * 16 + m] = c4[r];
    }
  }
}

extern "C" void kernel_launch(void* const* d_in, const int* in_sizes, int n_in,
                              void* d_out, int out_size, void* d_ws,
                              size_t ws_size, hipStream_t stream) {
  const float* feat = (const float*)d_in[0];
  const float* Wm = (const float*)d_in[1];
  const float* bm = (const float*)d_in[2];
  const float* Wl = (const float*)d_in[3];
  const float* bl = (const float*)d_in[4];
  const int* nbr0 = (const int*)d_in[5];
  const int* nbr1 = (const int*)d_in[6];
  const int* nbr2 = (const int*)d_in[7];
  float* out = (float*)d_out;
  float2* mlp2 = (float2*)d_ws;                               // 400 KB
  unsigned char* feat8 = (unsigned char*)d_ws + (512 << 10);  // 6.4 MB
  unsigned int* Whp =
      (unsigned int*)((char*)d_ws + (512 << 10) + (6400 << 10));  // 16 KB

  mlp_kernel<<<N_NODES / 8, 256, 0, stream>>>(feat, Wm, bm, Wl, mlp2, feat8,
                                              Whp);
  care_gemm_kernel<<<N_NODES / 16, 512, 0, stream>>>(
      feat, feat8, mlp2, nbr0, nbr1, nbr2, Whp, bl, out);
}

// Round 19
// 62.803 us; speedup vs baseline: 1.5986x; 1.5986x over previous
//
#include <hip/hip_runtime.h>
#include <hip/hip_fp16.h>

#define N_NODES 50000
#define K 32
#define NSEL 16
#define D 128
#define DOUT 64

typedef __attribute__((ext_vector_type(8))) _Float16 half8;
typedef __attribute__((ext_vector_type(4))) float floatx4;
typedef __attribute__((ext_vector_type(2))) float floatx2;

__device__ __forceinline__ unsigned int pack_h2(float a, float b) {
  union { __half2 h; unsigned int u; } c;
  c.h = __floats2half2_rn(a, b);
  return c.u;
}
__device__ __forceinline__ half8 as_h8(uint4 u) {
  union { uint4 u; half8 v; } c;
  c.u = u;
  return c.v;
}
__device__ __forceinline__ float fast_tanh(float x) {
  // 1 - 2/(1+e^{2x}). Exact at +/-inf.
  float e = __expf(2.f * x);
  return 1.f - __fdividef(2.f, 1.f + e);
}
__device__ __forceinline__ float agg_tanh(float s) {
  // tanh(s/16) = 1 - 2/(1+e^{s/8}); folds /16 and *2 into one constant.
  float e = __expf(s * 0.125f);
  return 1.f - __fdividef(2.f, 1.f + e);
}

// Kernel A: mlp2[n] = tanh(feat[n] @ W_mlp + b_mlp) (C=2), feat8 = fp8(feat).
// Blocks 0..15 additionally pre-pack W_lin into MFMA B-fragments (Whp).
// TWO nodes per wave. libm tanhf — mlp2 feeds top-k; fast tanh flips ties.
__global__ __launch_bounds__(256) void mlp_kernel(
    const float* __restrict__ feat, const float* __restrict__ Wm,
    const float* __restrict__ bm, const float* __restrict__ Wl,
    float2* __restrict__ mlp2,
    unsigned char* __restrict__ feat8 /* [N][D] fp8 e4m3, 128 B rows */,
    unsigned int* __restrict__ Whp /* 4096-word fp16 B-fragment table */) {
  const int wid = (blockIdx.x * blockDim.x + threadIdx.x) >> 6;  // 0..24999
  const int lane = threadIdx.x & 63;
  const int sub = lane & 31;
  const int n = wid * 2 + (lane >> 5);

  float4 f = *(const float4*)(feat + (size_t)n * D + sub * 4);
  float4 w01 = *(const float4*)(Wm + sub * 8);
  float4 w23 = *(const float4*)(Wm + sub * 8 + 4);
  float p0 = f.x * w01.x + f.y * w01.z + f.z * w23.x + f.w * w23.z;
  float p1 = f.x * w01.y + f.y * w01.w + f.z * w23.y + f.w * w23.w;
#pragma unroll
  for (int off = 16; off; off >>= 1) {  // stays within the 32-lane half
    p0 += __shfl_xor(p0, off);
    p1 += __shfl_xor(p1, off);
  }
  int pk8 = __builtin_amdgcn_cvt_pk_fp8_f32(f.x, f.y, 0, false);
  pk8 = __builtin_amdgcn_cvt_pk_fp8_f32(f.z, f.w, pk8, true);
  *(unsigned int*)(feat8 + ((size_t)n << 7) + (sub << 2)) = (unsigned int)pk8;
  if (sub == 0) {
    mlp2[n] = make_float2(tanhf(p0 + bm[0]), tanhf(p1 + bm[1]));
  }
  // W_lin fragment pre-pack: word wd = ((kk*4+nt)*64 + l)*4 + j2
  if (blockIdx.x < 16) {
    const int wd = blockIdx.x * 256 + threadIdx.x;  // 0..4095
    const int fr = wd >> 8, l = (wd >> 2) & 63, j2 = wd & 3;
    const int kk = fr >> 2, nt = fr & 3;
    const int k = kk * 32 + ((l >> 4) << 3) + 2 * j2;
    const int nn = nt * 16 + (l & 15);
    Whp[wd] = pack_h2(Wl[k * DOUT + nn], Wl[(k + 1) * DOUT + nn]);
  }
}

// Kernel B (fused): 512 threads = 8 waves = 16 nodes = one MFMA m-tile.
// Per wave: R11 care body (u64-key rank via ds_bpermute — EXACT top_k
// tie-break; fp8 gather, f32 pk accumulation in t-order). src is PRE-SHIFTED
// (<<7) through the rank permute so gather uses the permuted value directly
// as a 32-bit row byte-offset (saddr-form loads, no per-load shift/64b add).
// h packed fp16 into padded LDS sH[16][68]; one __syncthreads; waves 0..3
// compute one 16-col n-block of out = h @ W_lin + b via 4 fp16 MFMAs.
__global__ __launch_bounds__(512) void care_gemm_kernel(
    const float* __restrict__ feat, const unsigned char* __restrict__ feat8,
    const float2* __restrict__ mlp2, const int* __restrict__ nbr0,
    const int* __restrict__ nbr1, const int* __restrict__ nbr2,
    const unsigned int* __restrict__ Whp, const float* __restrict__ bl,
    float* __restrict__ out) {
  __shared__ __align__(16) unsigned int sW[4096];    // 16 KB B-fragments
  __shared__ __align__(16) unsigned int sH[16][68];  // 4.25 KB padded h rows

  const int tid = threadIdx.x;
  // Stage pre-packed W fragments: 4096 / 512 = 8 coalesced words each.
#pragma unroll
  for (int i = 0; i < 8; ++i) sW[tid + i * 512] = Whp[tid + i * 512];

  const int lane = tid & 63;
  const int sub = lane & 31;
  const int h = lane >> 5;
  const int w = tid >> 6;              // wave 0..7
  const int nl = w * 2 + h;            // node-local 0..15
  const int hbase = (lane & 32) << 2;  // DS byte addr of half's lane 0
  const int n = blockIdx.x * 16 + nl;  // grid = 3125 blocks exactly

  const float2 my = mlp2[n];
  float4 acc = *(const float4*)(feat + (size_t)n * D + sub * 4);  // residual

  // Phase 1: all edge ids + their mlp2 rows (6 loads in flight)
  const int src0 = nbr0[n * K + sub];
  const int src1 = nbr1[n * K + sub];
  const int src2 = nbr2[n * K + sub];
  const float2 mh0 = mlp2[src0];
  const float2 mh1 = mlp2[src1];
  const float2 mh2 = mlp2[src2];
  const float d0 = fabsf(mh0.x - my.x) + fabsf(mh0.y - my.y);
  const float d1 = fabsf(mh1.x - my.x) + fabsf(mh1.y - my.y);
  const float d2 = fabsf(mh2.x - my.x) + fabsf(mh2.y - my.y);

  // Phase 2: rank via u64 lexicographic keys (bit-exact top_k tie-break)
  const int b0 = __float_as_int(d0);
  const int b1 = __float_as_int(d1);
  const int b2 = __float_as_int(d2);
  const unsigned long long ki0 =
      ((unsigned long long)(unsigned)b0 << 32) | (unsigned)sub;
  const unsigned long long ki1 =
      ((unsigned long long)(unsigned)b1 << 32) | (unsigned)sub;
  const unsigned long long ki2 =
      ((unsigned long long)(unsigned)b2 << 32) | (unsigned)sub;
  int c0 = 0, c1 = 0, c2 = 0;
#pragma unroll
  for (int j = 0; j < K; ++j) {
    const int aj = hbase + 4 * j;
    const unsigned a0 = (unsigned)__builtin_amdgcn_ds_bpermute(aj, b0);
    const unsigned a1 = (unsigned)__builtin_amdgcn_ds_bpermute(aj, b1);
    const unsigned a2 = (unsigned)__builtin_amdgcn_ds_bpermute(aj, b2);
    c0 += (((unsigned long long)a0 << 32) | (unsigned)j) < ki0;
    c1 += (((unsigned long long)a1 << 32) | (unsigned)j) < ki1;
    c2 += (((unsigned long long)a2 << 32) | (unsigned)j) < ki2;
  }

  // push PRE-SHIFTED src (row byte-offset) to lane hbase/4 + rank
  int p0 = __builtin_amdgcn_ds_permute(hbase + (c0 << 2), src0 << 7);
  int p1 = __builtin_amdgcn_ds_permute(hbase + (c1 << 2), src1 << 7);
  int p2 = __builtin_amdgcn_ds_permute(hbase + (c2 << 2), src2 << 7);

  // Phase 3: merged gather — 32-bit indices off the uniform feat8 base
  // (saddr-form loads), packed f32 accumulation in t-order.
  const unsigned off4 = (unsigned)sub << 2;
  floatx2 A00 = {0.f, 0.f}, A01 = {0.f, 0.f};
  floatx2 A10 = {0.f, 0.f}, A11 = {0.f, 0.f};
  floatx2 A20 = {0.f, 0.f}, A21 = {0.f, 0.f};
#pragma unroll
  for (int t = 0; t < NSEL; ++t) {
    const int at = hbase + 4 * t;
    const unsigned r0 = (unsigned)__builtin_amdgcn_ds_bpermute(at, p0);
    const unsigned r1 = (unsigned)__builtin_amdgcn_ds_bpermute(at, p1);
    const unsigned r2 = (unsigned)__builtin_amdgcn_ds_bpermute(at, p2);
    const unsigned w0 = *(const unsigned*)(feat8 + (r0 | off4));
    const unsigned w1 = *(const unsigned*)(feat8 + (r1 | off4));
    const unsigned w2 = *(const unsigned*)(feat8 + (r2 | off4));
    A00 += __builtin_amdgcn_cvt_pk_f32_fp8(w0, false);
    A01 += __builtin_amdgcn_cvt_pk_f32_fp8(w0, true);
    A10 += __builtin_amdgcn_cvt_pk_f32_fp8(w1, false);
    A11 += __builtin_amdgcn_cvt_pk_f32_fp8(w1, true);
    A20 += __builtin_amdgcn_cvt_pk_f32_fp8(w2, false);
    A21 += __builtin_amdgcn_cvt_pk_f32_fp8(w2, true);
  }
  acc.x += 0.5f * agg_tanh(A00.x);
  acc.y += 0.5f * agg_tanh(A00.y);
  acc.z += 0.5f * agg_tanh(A01.x);
  acc.w += 0.5f * agg_tanh(A01.y);
  acc.x += 0.5f * agg_tanh(A10.x);
  acc.y += 0.5f * agg_tanh(A10.y);
  acc.z += 0.5f * agg_tanh(A11.x);
  acc.w += 0.5f * agg_tanh(A11.y);
  acc.x += 0.5f * agg_tanh(A20.x);
  acc.y += 0.5f * agg_tanh(A20.y);
  acc.z += 0.5f * agg_tanh(A21.x);
  acc.w += 0.5f * agg_tanh(A21.y);

  acc.x = fast_tanh(acc.x);
  acc.y = fast_tanh(acc.y);
  acc.z = fast_tanh(acc.z);
  acc.w = fast_tanh(acc.w);
  uint2 hp;
  hp.x = pack_h2(acc.x, acc.y);
  hp.y = pack_h2(acc.z, acc.w);
  *(uint2*)&sH[nl][sub * 2] = hp;  // h row in LDS (fp16-packed)
  __syncthreads();                 // covers sW staging + sH writes

  // Matmul epilogue: waves 0..3, one 16-col n-block each; 4 MFMAs over K=128.
  if (w < 4) {
    const int nt = w;
    const int m = lane & 15;
    const int koff = (lane >> 4) * 4;  // word offset inside 16-word k-chunk
    float bn = bl[nt * 16 + m];
    floatx4 c4 = {bn, bn, bn, bn};
#pragma unroll
    for (int kk = 0; kk < 4; ++kk) {
      uint4 aw = *(const uint4*)&sH[m][kk * 16 + koff];
      uint4 bw = *(const uint4*)&sW[(kk * 4 + nt) * 256 + lane * 4];
      c4 = __builtin_amdgcn_mfma_f32_16x16x32_f16(as_h8(aw), as_h8(bw), c4, 0,
                                                  0, 0);
    }
#pragma unroll
    for (int r = 0; r < 4; ++r) {
      const int mr = ((lane >> 4) << 2) + r;
      out[(size_t)(blockIdx.x * 16 + mr) * DOUT + nt * 16 + m] = c4[r];
    }
  }
}

extern "C" void kernel_launch(void* const* d_in, const int* in_sizes, int n_in,
                              void* d_out, int out_size, void* d_ws,
                              size_t ws_size, hipStream_t stream) {
  const float* feat = (const float*)d_in[0];
  const float* Wm = (const float*)d_in[1];
  const float* bm = (const float*)d_in[2];
  const float* Wl = (const float*)d_in[3];
  const float* bl = (const float*)d_in[4];
  const int* nbr0 = (const int*)d_in[5];
  const int* nbr1 = (const int*)d_in[6];
  const int* nbr2 = (const int*)d_in[7];
  float* out = (float*)d_out;
  float2* mlp2 = (float2*)d_ws;                               // 400 KB
  unsigned char* feat8 = (unsigned char*)d_ws + (512 << 10);  // 6.4 MB
  unsigned int* Whp =
      (unsigned int*)((char*)d_ws + (512 << 10) + (6400 << 10));  // 16 KB

  mlp_kernel<<<N_NODES / 8, 256, 0, stream>>>(feat, Wm, bm, Wl, mlp2, feat8,
                                              Whp);
  care_gemm_kernel<<<N_NODES / 16, 512, 0, stream>>>(
      feat, feat8, mlp2, nbr0, nbr1, nbr2, Whp, bl, out);
}